// Round 18
// baseline (223.636 us; speedup 1.0000x reference)
//
#include <hip/hip_runtime.h>
#include <math.h>

// B=8, L=512, H=768, T=9, HEADS=12, d=64
//   Q = hs@Wq + bq ; K = hs@Wk + bk  (M=4096, N=6912, K=768)  -> RoPE -> bf16
//   score[b,i,j,t] = (1/96) * Qr[b*512+i, t*768:+768] . Kr[b*512+j, t*768:+768]
// R17: score restructured to 128x128 spatial tile x t-PAIRS (block = b,it,jt,tg;
// tg covers t=2tg,2tg+1). Uses rope's proven 128x128 BK=64 engine (64x64 wave
// tiles -> LDS reads/DMA per MFMA halved vs the 64x64-spatial version).
// Output: 2 floats per cell per block; XCD=batch + tg-fastest dispatch makes
// the 5 sibling blocks' partial-line writes merge in one L2 (WRITE_SIZE is the
// discriminator). rope + prep frozen at R13/R16.

typedef __attribute__((ext_vector_type(4))) float f32x4;
typedef __attribute__((ext_vector_type(8))) __bf16 bf16x8;
typedef __attribute__((ext_vector_type(8))) unsigned short ushort8;

#define HH   768
#define NCOL 6912
#define LL   512
#define NT   12      // K-tiles of 64

static __device__ __forceinline__ unsigned short f2bf(float f) {
  unsigned int u = __float_as_uint(f);
  u += 0x7FFFu + ((u >> 16) & 1u);
  return (unsigned short)(u >> 16);
}

static __device__ __forceinline__ void async16(const void* g, void* l) {
  __builtin_amdgcn_global_load_lds(
      (const __attribute__((address_space(1))) unsigned int*)g,
      (__attribute__((address_space(3))) unsigned int*)l, 16, 0, 0);
}

// ---------------- fused prep kernel ----------------

__global__ void k_prep(const float4* __restrict__ hs4, ushort8* __restrict__ hsb8,
                       const float* __restrict__ Wq, const float* __restrict__ Wk,
                       unsigned short* __restrict__ Wtq, unsigned short* __restrict__ Wtk,
                       float2* __restrict__ sc) {
  __shared__ float tile[32][33];
  const int bid = blockIdx.x;
  const int tid = threadIdx.x;
  if (bid < 1536) {
    int idx = bid * 256 + tid;
    float4 a = hs4[idx * 2], b = hs4[idx * 2 + 1];
    ushort8 o;
    o[0] = f2bf(a.x); o[1] = f2bf(a.y); o[2] = f2bf(a.z); o[3] = f2bf(a.w);
    o[4] = f2bf(b.x); o[5] = f2bf(b.y); o[6] = f2bf(b.z); o[7] = f2bf(b.w);
    hsb8[idx] = o;
  } else if (bid < 11904) {
    const int tb = bid - 1536;              // 10368 = 2z * 24k * 216n
    const int zz = tb / 5184, rem = tb % 5184;
    const int n0 = (rem % 216) * 32, k0 = (rem / 216) * 32;
    const float* W = zz ? Wk : Wq;
    unsigned short* Wt = zz ? Wtk : Wtq;
    const int tx = tid & 31, ty0 = tid >> 5;  // 32 x 8
#pragma unroll
    for (int j = 0; j < 4; ++j) {
      int ty = ty0 + j * 8;
      tile[ty][tx] = W[(size_t)(k0 + ty) * NCOL + n0 + tx];
    }
    __syncthreads();
#pragma unroll
    for (int j = 0; j < 4; ++j) {
      int ty = ty0 + j * 8;
      int n = n0 + ty;
      int c = n & 63;
      int gc = ((c & 1) << 4) | ((c >> 5) << 5) | ((c & 31) >> 1);
      int np = (n & ~63) | gc;
      Wt[(size_t)np * HH + k0 + tx] = f2bf(tile[tx][ty]);
    }
  } else {
    int idx = (bid - 11904) * 256 + tid;    // 16384
    int i = idx >> 5, p = idx & 31;
    double ang = (double)i * pow(10000.0, -(double)p / 32.0);
    sc[idx] = make_float2((float)sin(ang), (float)cos(ang));
  }
}

// ---------------- 128x128 BK=64 dbuf counted-vmcnt engine (rope) ----------------

template <int STR>
static __device__ __forceinline__ void k2_loop(
    const unsigned short* __restrict__ aSrc, const unsigned short* __restrict__ bSrc,
    char* smem, int tid, f32x4 acc[4][4]) {
  const int lane = tid & 63, wid = tid >> 6;
  const int wr = wid >> 1, wc = wid & 1;
  const int ldsW = wid * 1024;
  const int aRdBase = (wr * 64 + (lane & 15)) * 128;
  const int bRdBase = (wc * 64 + (lane & 15)) * 128;
  const int aci0 = ((lane >> 4) ^ (lane & 7)) << 4;
  const int aci1 = ((4 + (lane >> 4)) ^ (lane & 7)) << 4;

  auto stage = [&](int bb, int kt) {
#pragma unroll
    for (int j = 0; j < 4; ++j) {
      async16(aSrc + (size_t)(j * 32) * STR + kt * 64,
              smem + bb * 32768 + j * 4096 + ldsW);
      async16(bSrc + (size_t)(j * 32) * STR + kt * 64,
              smem + bb * 32768 + 16384 + j * 4096 + ldsW);
    }
  };

  stage(0, 0);
  int cur = 0;
  for (int t = 0; t < NT; ++t) {
    const int ktn = (t + 1 < NT) ? t + 1 : NT - 1;
    stage(cur ^ 1, ktn);
    asm volatile("s_waitcnt vmcnt(8)" ::: "memory");
    __builtin_amdgcn_s_barrier();

    char* AB = smem + cur * 32768;
    char* BB = AB + 16384;
    bf16x8 Af[4][2], Bf[4][2];
#pragma unroll
    for (int mf = 0; mf < 4; ++mf) {
      Af[mf][0] = *(const bf16x8*)(AB + aRdBase + mf * 2048 + aci0);
      Af[mf][1] = *(const bf16x8*)(AB + aRdBase + mf * 2048 + aci1);
    }
#pragma unroll
    for (int nf = 0; nf < 4; ++nf) {
      Bf[nf][0] = *(const bf16x8*)(BB + bRdBase + nf * 2048 + aci0);
      Bf[nf][1] = *(const bf16x8*)(BB + bRdBase + nf * 2048 + aci1);
    }
#pragma unroll
    for (int kk = 0; kk < 2; ++kk)
#pragma unroll
      for (int mf = 0; mf < 4; ++mf)
#pragma unroll
        for (int nf = 0; nf < 4; ++nf)
          acc[mf][nf] = __builtin_amdgcn_mfma_f32_16x16x32_bf16(
              Af[mf][kk], Bf[nf][kk], acc[mf][nf], 0, 0, 0);
    __builtin_amdgcn_s_barrier();
    cur ^= 1;
  }
}

// ---------------- GEMM1: projection + bias + RoPE -> bf16 (frozen) ----------------

__global__ __launch_bounds__(256) void k2_rope(
    const unsigned short* __restrict__ hsb,
    const unsigned short* __restrict__ Wtq, const unsigned short* __restrict__ Wtk,
    const float* __restrict__ bq, const float* __restrict__ bk,
    const float2* __restrict__ sc,
    unsigned short* __restrict__ Qr, unsigned short* __restrict__ Kr) {
  __shared__ __align__(16) char smem[65536];
  const int bid = blockIdx.x;
  const int xcd = bid & 7, idx = bid >> 3;
  const int st = xcd * 9 + idx / 48;
  const int u = idx % 48;
  const int dm = u & 7, dn = u >> 3;
  const int z = st / 36, r = st % 36;
  const int smr = r & 3, snc = r >> 2;
  const int mtile = smr * 8 + dm;
  const int ntile = snc * 6 + dn;
  const unsigned short* Wt = z ? Wtk : Wtq;
  const float* bias = z ? bk : bq;
  unsigned short* outp = z ? Kr : Qr;
  const int m0 = mtile * 128, n0 = ntile * 128;
  const int tid = threadIdx.x;
  const int lane = tid & 63, wid = tid >> 6;
  const int wr = wid >> 1, wc = wid & 1;

  const int row_in = tid >> 3;
  const int ci_u = (tid & 7) ^ (row_in & 7);
  const unsigned short* aSrc = hsb + (size_t)(m0 + row_in) * HH + ci_u * 8;
  const unsigned short* bSrc = Wt + (size_t)(n0 + row_in) * HH + ci_u * 8;

  f32x4 acc[4][4] = {};
  k2_loop<HH>(aSrc, bSrc, smem, tid, acc);

  const int cA = n0 + wc * 64;
  const int e0 = lane & 15, e1 = 16 + e0;
  const float b1a = bias[cA + 2 * e0], b2a = bias[cA + 2 * e0 + 1];
  const float b1b = bias[cA + 2 * e1], b2b = bias[cA + 2 * e1 + 1];

#pragma unroll
  for (int mf = 0; mf < 4; ++mf) {
    const int rbase = m0 + wr * 64 + mf * 16 + (lane >> 4) * 4;
#pragma unroll
    for (int q = 0; q < 4; ++q) {
      const int grow = rbase + q;
      const int i = grow & (LL - 1);
      float2 s0 = sc[i * 32 + e0];
      float2 s1 = sc[i * 32 + e1];
      float x1 = acc[mf][0][q] + b1a, x2 = acc[mf][1][q] + b2a;
      float y1 = acc[mf][2][q] + b1b, y2 = acc[mf][3][q] + b2b;
      size_t ro = (size_t)grow * NCOL + cA;
      outp[ro + e0]      = f2bf(x1 * s0.y - x2 * s0.x);
      outp[ro + e0 + 32] = f2bf(x2 * s0.y + x1 * s0.x);
      outp[ro + e1]      = f2bf(y1 * s1.y - y2 * s1.x);
      outp[ro + e1 + 32] = f2bf(y2 * s1.y + y1 * s1.x);
    }
  }
}

// ---------------- GEMM2: score, 128x128 spatial x t-pair ----------------
// Block (b, it, jt, tg): t = {2tg, 2tg+1} (tg=4 -> t=8 only). Flat pipeline
// over nt*12 K-tiles (column jumps at t boundary), rope-engine body (64x64
// wave tiles). Epilogue: 2 floats per (i,j) cell at out[...*9 + 2tg].

__global__ __launch_bounds__(256, 2) void kts_score(
    const unsigned short* __restrict__ Qr, const unsigned short* __restrict__ Kr,
    float* __restrict__ out) {
  __shared__ __align__(16) char smem[65536];
  const int bid = blockIdx.x;               // 640 = 8b * 16(it,jt) * 5tg
  const int b = bid & 7;                    // XCD = batch
  const int idx = bid >> 3;                 // 0..79
  const int tg = idx % 5;                   // fastest -> 5 siblings consecutive
  const int rest = idx / 5;                 // 0..15
  const int it = rest >> 2, jt = rest & 3;
  const int t0 = tg * 2;
  const int nt = (tg < 4) ? 2 : 1;
  const int tid = threadIdx.x;
  const int lane = tid & 63, wid = tid >> 6;
  const int wr = wid >> 1, wc = wid & 1;
  const int ldsW = wid * 1024;

  const int row_in = tid >> 3;
  const int ci_u = (tid & 7) ^ (row_in & 7);
  const unsigned short* aSrc = Qr + (size_t)(b * 512 + it * 128 + row_in) * NCOL + ci_u * 8;
  const unsigned short* bSrc = Kr + (size_t)(b * 512 + jt * 128 + row_in) * NCOL + ci_u * 8;

  auto stage = [&](int bb, int g) {        // g in [0, nt*12)
    const int c = (t0 + g / 12) * HH + (g % 12) * 64;
#pragma unroll
    for (int j = 0; j < 4; ++j) {
      async16(aSrc + (size_t)(j * 32) * NCOL + c,
              smem + bb * 32768 + j * 4096 + ldsW);
      async16(bSrc + (size_t)(j * 32) * NCOL + c,
              smem + bb * 32768 + 16384 + j * 4096 + ldsW);
    }
  };

  const int rl = lane & 15;
  const int aRdBase = (wr * 64 + rl) * 128;
  const int bRdBase = (wc * 64 + rl) * 128;
  const int aci0 = ((lane >> 4) ^ (lane & 7)) << 4;
  const int aci1 = ((4 + (lane >> 4)) ^ (lane & 7)) << 4;

  f32x4 acc[2][4][4] = {};
  const int G = nt * 12;

  stage(0, 0);
#pragma unroll
  for (int tt = 0; tt < 2; ++tt) {
    if (tt >= nt) break;                   // wave-uniform guard; acc index static
    for (int kt = 0; kt < 12; ++kt) {
      const int g = tt * 12 + kt;
      const int cur = g & 1;
      if (g < G - 1) {
        stage(cur ^ 1, g + 1);
        asm volatile("s_waitcnt vmcnt(8)" ::: "memory");
      } else {
        asm volatile("s_waitcnt vmcnt(0)" ::: "memory");
      }
      __builtin_amdgcn_s_barrier();

      char* AB = smem + cur * 32768;
      char* BB = AB + 16384;
      bf16x8 Af[4][2], Bf[4][2];
#pragma unroll
      for (int mf = 0; mf < 4; ++mf) {
        Af[mf][0] = *(const bf16x8*)(AB + aRdBase + mf * 2048 + aci0);
        Af[mf][1] = *(const bf16x8*)(AB + aRdBase + mf * 2048 + aci1);
      }
#pragma unroll
      for (int nf = 0; nf < 4; ++nf) {
        Bf[nf][0] = *(const bf16x8*)(BB + bRdBase + nf * 2048 + aci0);
        Bf[nf][1] = *(const bf16x8*)(BB + bRdBase + nf * 2048 + aci1);
      }
#pragma unroll
      for (int kk = 0; kk < 2; ++kk)
#pragma unroll
        for (int mf = 0; mf < 4; ++mf)
#pragma unroll
          for (int nf = 0; nf < 4; ++nf)
            acc[tt][mf][nf] = __builtin_amdgcn_mfma_f32_16x16x32_bf16(
                Af[mf][kk], Bf[nf][kk], acc[tt][mf][nf], 0, 0, 0);
      __builtin_amdgcn_s_barrier();
    }
  }

  // epilogue: 2 (or 1) floats per (i,j) cell at t-offset t0
  const float SC = 0.125f / 12.0f;   // 64^-0.5 / 12
#pragma unroll
  for (int mf = 0; mf < 4; ++mf)
#pragma unroll
    for (int q = 0; q < 4; ++q) {
      const int i = it * 128 + wr * 64 + mf * 16 + (lane >> 4) * 4 + q;
#pragma unroll
      for (int nf = 0; nf < 4; ++nf) {
        const int j = jt * 128 + wc * 64 + nf * 16 + rl;
        float* o = out + ((size_t)(b * 512 + i) * 512 + j) * 9 + t0;
        o[0] = acc[0][mf][nf][q] * SC;
        if (nt == 2) o[1] = acc[1][mf][nf][q] * SC;
      }
    }
}

// ---------------- launch ----------------

extern "C" void kernel_launch(void* const* d_in, const int* in_sizes, int n_in,
                              void* d_out, int out_size, void* d_ws, size_t ws_size,
                              hipStream_t stream) {
  const float* hs = (const float*)d_in[0];
  const float* Wq = (const float*)d_in[1];
  const float* bq = (const float*)d_in[2];
  const float* Wk = (const float*)d_in[3];
  const float* bk = (const float*)d_in[4];
  float* out = (float*)d_out;
  char* ws = (char*)d_ws;

  float2* sctab = (float2*)(ws);                               //  131072
  unsigned short* hsb = (unsigned short*)(ws + 131072);        // 6291456
  unsigned short* Wtq = (unsigned short*)(ws + 6422528);       // 10616832
  unsigned short* Wtk = (unsigned short*)(ws + 17039360);      // 10616832
  unsigned short* Qr  = (unsigned short*)(ws + 27656192);      // 56623104
  unsigned short* Kr  = (unsigned short*)(ws + 84279296);      // 56623104 -> 140902400

  hipLaunchKernelGGL(k_prep, dim3(11968), dim3(256), 0, stream,
                     (const float4*)hs, (ushort8*)hsb, Wq, Wk, Wtq, Wtk, sctab);
  hipLaunchKernelGGL(k2_rope, dim3(3456), dim3(256), 0, stream,
                     hsb, Wtq, Wtk, bq, bk, sctab, Qr, Kr);
  hipLaunchKernelGGL(kts_score, dim3(640), dim3(256), 0, stream, Qr, Kr, out);
}

// Round 19
// 186.631 us; speedup vs baseline: 1.1983x; 1.1983x over previous
//
#include <hip/hip_runtime.h>
#include <math.h>

// B=8, L=512, H=768, T=9, HEADS=12, d=64
//   Q = hs@Wq + bq ; K = hs@Wk + bk  (M=4096, N=6912, K=768)  -> RoPE -> bf16
//   score[b,i,j,t] = (1/96) * Qr[b*512+i, t*768:+768] . Kr[b*512+j, t*768:+768]
// R18 = R13/R16 (final, best measured 187.1us). All alternatives measured worse:
//   rope: 8-phase x3, lookahead, BK32, 128x192, z-fused, direct-B x2 -> >=114us
//   score: BK128 (+18us), packed stores (+3us), t-pair 128^2 (+36us, write-amp)
// Components:
//   k_prep  : fused conversion/transpose/tables (~3.5us)
//   k2_rope : 128x128 BK=64 dbuf counted-vmcnt + L2 supertiles (114us)
//   k9_score: t-fused 64x64 BK=64, contiguous scalar 9-float writes (~60us)

typedef __attribute__((ext_vector_type(4))) float f32x4;
typedef __attribute__((ext_vector_type(8))) __bf16 bf16x8;
typedef __attribute__((ext_vector_type(8))) unsigned short ushort8;

#define HH   768
#define NCOL 6912
#define LL   512
#define NT   12      // K-tiles of 64

static __device__ __forceinline__ unsigned short f2bf(float f) {
  unsigned int u = __float_as_uint(f);
  u += 0x7FFFu + ((u >> 16) & 1u);
  return (unsigned short)(u >> 16);
}

static __device__ __forceinline__ void async16(const void* g, void* l) {
  __builtin_amdgcn_global_load_lds(
      (const __attribute__((address_space(1))) unsigned int*)g,
      (__attribute__((address_space(3))) unsigned int*)l, 16, 0, 0);
}

// ---------------- fused prep kernel ----------------

__global__ void k_prep(const float4* __restrict__ hs4, ushort8* __restrict__ hsb8,
                       const float* __restrict__ Wq, const float* __restrict__ Wk,
                       unsigned short* __restrict__ Wtq, unsigned short* __restrict__ Wtk,
                       float2* __restrict__ sc) {
  __shared__ float tile[32][33];
  const int bid = blockIdx.x;
  const int tid = threadIdx.x;
  if (bid < 1536) {
    int idx = bid * 256 + tid;
    float4 a = hs4[idx * 2], b = hs4[idx * 2 + 1];
    ushort8 o;
    o[0] = f2bf(a.x); o[1] = f2bf(a.y); o[2] = f2bf(a.z); o[3] = f2bf(a.w);
    o[4] = f2bf(b.x); o[5] = f2bf(b.y); o[6] = f2bf(b.z); o[7] = f2bf(b.w);
    hsb8[idx] = o;
  } else if (bid < 11904) {
    const int tb = bid - 1536;              // 10368 = 2z * 24k * 216n
    const int zz = tb / 5184, rem = tb % 5184;
    const int n0 = (rem % 216) * 32, k0 = (rem / 216) * 32;
    const float* W = zz ? Wk : Wq;
    unsigned short* Wt = zz ? Wtk : Wtq;
    const int tx = tid & 31, ty0 = tid >> 5;  // 32 x 8
#pragma unroll
    for (int j = 0; j < 4; ++j) {
      int ty = ty0 + j * 8;
      tile[ty][tx] = W[(size_t)(k0 + ty) * NCOL + n0 + tx];
    }
    __syncthreads();
#pragma unroll
    for (int j = 0; j < 4; ++j) {
      int ty = ty0 + j * 8;
      int n = n0 + ty;
      int c = n & 63;
      int gc = ((c & 1) << 4) | ((c >> 5) << 5) | ((c & 31) >> 1);
      int np = (n & ~63) | gc;
      Wt[(size_t)np * HH + k0 + tx] = f2bf(tile[tx][ty]);
    }
  } else {
    int idx = (bid - 11904) * 256 + tid;    // 16384
    int i = idx >> 5, p = idx & 31;
    double ang = (double)i * pow(10000.0, -(double)p / 32.0);
    sc[idx] = make_float2((float)sin(ang), (float)cos(ang));
  }
}

// ---------------- 128x128 BK=64 dbuf counted-vmcnt engine (rope) ----------------

template <int STR>
static __device__ __forceinline__ void k2_loop(
    const unsigned short* __restrict__ aSrc, const unsigned short* __restrict__ bSrc,
    char* smem, int tid, f32x4 acc[4][4]) {
  const int lane = tid & 63, wid = tid >> 6;
  const int wr = wid >> 1, wc = wid & 1;
  const int ldsW = wid * 1024;
  const int aRdBase = (wr * 64 + (lane & 15)) * 128;
  const int bRdBase = (wc * 64 + (lane & 15)) * 128;
  const int aci0 = ((lane >> 4) ^ (lane & 7)) << 4;
  const int aci1 = ((4 + (lane >> 4)) ^ (lane & 7)) << 4;

  auto stage = [&](int bb, int kt) {
#pragma unroll
    for (int j = 0; j < 4; ++j) {
      async16(aSrc + (size_t)(j * 32) * STR + kt * 64,
              smem + bb * 32768 + j * 4096 + ldsW);
      async16(bSrc + (size_t)(j * 32) * STR + kt * 64,
              smem + bb * 32768 + 16384 + j * 4096 + ldsW);
    }
  };

  stage(0, 0);
  int cur = 0;
  for (int t = 0; t < NT; ++t) {
    const int ktn = (t + 1 < NT) ? t + 1 : NT - 1;
    stage(cur ^ 1, ktn);
    asm volatile("s_waitcnt vmcnt(8)" ::: "memory");
    __builtin_amdgcn_s_barrier();

    char* AB = smem + cur * 32768;
    char* BB = AB + 16384;
    bf16x8 Af[4][2], Bf[4][2];
#pragma unroll
    for (int mf = 0; mf < 4; ++mf) {
      Af[mf][0] = *(const bf16x8*)(AB + aRdBase + mf * 2048 + aci0);
      Af[mf][1] = *(const bf16x8*)(AB + aRdBase + mf * 2048 + aci1);
    }
#pragma unroll
    for (int nf = 0; nf < 4; ++nf) {
      Bf[nf][0] = *(const bf16x8*)(BB + bRdBase + nf * 2048 + aci0);
      Bf[nf][1] = *(const bf16x8*)(BB + bRdBase + nf * 2048 + aci1);
    }
#pragma unroll
    for (int kk = 0; kk < 2; ++kk)
#pragma unroll
      for (int mf = 0; mf < 4; ++mf)
#pragma unroll
        for (int nf = 0; nf < 4; ++nf)
          acc[mf][nf] = __builtin_amdgcn_mfma_f32_16x16x32_bf16(
              Af[mf][kk], Bf[nf][kk], acc[mf][nf], 0, 0, 0);
    __builtin_amdgcn_s_barrier();
    cur ^= 1;
  }
}

// ---------------- GEMM1: projection + bias + RoPE -> bf16 ----------------

__global__ __launch_bounds__(256) void k2_rope(
    const unsigned short* __restrict__ hsb,
    const unsigned short* __restrict__ Wtq, const unsigned short* __restrict__ Wtk,
    const float* __restrict__ bq, const float* __restrict__ bk,
    const float2* __restrict__ sc,
    unsigned short* __restrict__ Qr, unsigned short* __restrict__ Kr) {
  __shared__ __align__(16) char smem[65536];
  // L2 supertile decode: xcd=bid&7, supertile 8m x 6n (~2.7MB < 4MB L2).
  const int bid = blockIdx.x;
  const int xcd = bid & 7, idx = bid >> 3;
  const int st = xcd * 9 + idx / 48;
  const int u = idx % 48;
  const int dm = u & 7, dn = u >> 3;
  const int z = st / 36, r = st % 36;
  const int smr = r & 3, snc = r >> 2;
  const int mtile = smr * 8 + dm;
  const int ntile = snc * 6 + dn;
  const unsigned short* Wt = z ? Wtk : Wtq;
  const float* bias = z ? bk : bq;
  unsigned short* outp = z ? Kr : Qr;
  const int m0 = mtile * 128, n0 = ntile * 128;
  const int tid = threadIdx.x;
  const int lane = tid & 63, wid = tid >> 6;
  const int wr = wid >> 1, wc = wid & 1;

  const int row_in = tid >> 3;
  const int ci_u = (tid & 7) ^ (row_in & 7);
  const unsigned short* aSrc = hsb + (size_t)(m0 + row_in) * HH + ci_u * 8;
  const unsigned short* bSrc = Wt + (size_t)(n0 + row_in) * HH + ci_u * 8;

  f32x4 acc[4][4] = {};
  k2_loop<HH>(aSrc, bSrc, smem, tid, acc);

  const int cA = n0 + wc * 64;
  const int e0 = lane & 15, e1 = 16 + e0;
  const float b1a = bias[cA + 2 * e0], b2a = bias[cA + 2 * e0 + 1];
  const float b1b = bias[cA + 2 * e1], b2b = bias[cA + 2 * e1 + 1];

#pragma unroll
  for (int mf = 0; mf < 4; ++mf) {
    const int rbase = m0 + wr * 64 + mf * 16 + (lane >> 4) * 4;
#pragma unroll
    for (int q = 0; q < 4; ++q) {
      const int grow = rbase + q;
      const int i = grow & (LL - 1);
      float2 s0 = sc[i * 32 + e0];
      float2 s1 = sc[i * 32 + e1];
      float x1 = acc[mf][0][q] + b1a, x2 = acc[mf][1][q] + b2a;
      float y1 = acc[mf][2][q] + b1b, y2 = acc[mf][3][q] + b2b;
      size_t ro = (size_t)grow * NCOL + cA;
      outp[ro + e0]      = f2bf(x1 * s0.y - x2 * s0.x);
      outp[ro + e0 + 32] = f2bf(x2 * s0.y + x1 * s0.x);
      outp[ro + e1]      = f2bf(y1 * s1.y - y2 * s1.x);
      outp[ro + e1 + 32] = f2bf(y2 * s1.y + y1 * s1.x);
    }
  }
}

// ---------------- GEMM2: score, t-FUSED 64x64 tile, BK=64 ----------------

__global__ __launch_bounds__(256, 2) void k9_score(
    const unsigned short* __restrict__ Qr, const unsigned short* __restrict__ Kr,
    float* __restrict__ out) {
  __shared__ __align__(16) char smem[32768];
  const int bid = blockIdx.x;                 // 512 = 8b * 16s * 4q
  const int b = bid & 7, idx = bid >> 3;      // XCD = batch
  const int s = idx >> 2, q4 = idx & 3;       // 2x2 (it,jt) supertiles
  const int it = (s >> 2) * 2 + (q4 >> 1);    // 0..7
  const int jt = (s & 3) * 2 + (q4 & 1);      // 0..7
  const int tid = threadIdx.x;
  const int lane = tid & 63, wid = tid >> 6;
  const int wr = wid >> 1, wc = wid & 1;

  const int srow = wid * 8 + (lane >> 3);
  const int sch = (lane & 7) ^ (lane >> 3);
  const unsigned short* aBase = Qr + (size_t)(b * 512 + it * 64 + srow) * NCOL + sch * 8;
  const unsigned short* bBase = Kr + (size_t)(b * 512 + jt * 64 + srow) * NCOL + sch * 8;

  auto stage = [&](int bb, int g) {
    const unsigned short* ga = aBase + g * 64;
    const unsigned short* gb = bBase + g * 64;
    char* l = smem + bb * 16384 + wid * 1024;
    async16(ga, l);
    async16(ga + (size_t)32 * NCOL, l + 4096);
    async16(gb, l + 8192);
    async16(gb + (size_t)32 * NCOL, l + 12288);
  };

  const int aR0 = (wr * 32 + (lane & 15)) * 128;
  const int bR0 = (wc * 32 + (lane & 15)) * 128;
  const int ar7 = (wr * 32 + (lane & 15)) & 7;
  const int br7 = (wc * 32 + (lane & 15)) & 7;
  const int cc0 = lane >> 4;
  const int aci0 = ((cc0) ^ ar7) << 4, aci1 = ((4 + cc0) ^ ar7) << 4;
  const int bci0 = ((cc0) ^ br7) << 4, bci1 = ((4 + cc0) ^ br7) << 4;

  f32x4 acc[9][2][2] = {};

  stage(0, 0);
#pragma unroll
  for (int tt = 0; tt < 9; ++tt) {
    for (int kt = 0; kt < 12; ++kt) {
      const int g = tt * 12 + kt;
      const int cur = g & 1;
      if (g < 107) {
        stage(cur ^ 1, g + 1);
        asm volatile("s_waitcnt vmcnt(4)" ::: "memory");
      } else {
        asm volatile("s_waitcnt vmcnt(0)" ::: "memory");
      }
      __builtin_amdgcn_s_barrier();

      char* AB = smem + cur * 16384;
      char* BB = AB + 8192;
      bf16x8 Af[2][2], Bf[2][2];
#pragma unroll
      for (int mf = 0; mf < 2; ++mf) {
        Af[mf][0] = *(const bf16x8*)(AB + aR0 + mf * 2048 + aci0);
        Af[mf][1] = *(const bf16x8*)(AB + aR0 + mf * 2048 + aci1);
      }
#pragma unroll
      for (int nf = 0; nf < 2; ++nf) {
        Bf[nf][0] = *(const bf16x8*)(BB + bR0 + nf * 2048 + bci0);
        Bf[nf][1] = *(const bf16x8*)(BB + bR0 + nf * 2048 + bci1);
      }
#pragma unroll
      for (int kk = 0; kk < 2; ++kk)
#pragma unroll
        for (int mf = 0; mf < 2; ++mf)
#pragma unroll
          for (int nf = 0; nf < 2; ++nf)
            acc[tt][mf][nf] = __builtin_amdgcn_mfma_f32_16x16x32_bf16(
                Af[mf][kk], Bf[nf][kk], acc[tt][mf][nf], 0, 0, 0);
      __builtin_amdgcn_s_barrier();
    }
  }

  const float SC = 0.125f / 12.0f;   // 64^-0.5 / 12
#pragma unroll
  for (int mf = 0; mf < 2; ++mf)
#pragma unroll
    for (int q = 0; q < 4; ++q) {
      const int i = it * 64 + wr * 32 + mf * 16 + (lane >> 4) * 4 + q;
#pragma unroll
      for (int nf = 0; nf < 2; ++nf) {
        const int j = jt * 64 + wc * 32 + nf * 16 + (lane & 15);
        float* o = out + ((size_t)(b * 512 + i) * 512 + j) * 9;
#pragma unroll
        for (int t = 0; t < 9; ++t)
          o[t] = acc[t][mf][nf][q] * SC;
      }
    }
}

// ---------------- launch ----------------

extern "C" void kernel_launch(void* const* d_in, const int* in_sizes, int n_in,
                              void* d_out, int out_size, void* d_ws, size_t ws_size,
                              hipStream_t stream) {
  const float* hs = (const float*)d_in[0];
  const float* Wq = (const float*)d_in[1];
  const float* bq = (const float*)d_in[2];
  const float* Wk = (const float*)d_in[3];
  const float* bk = (const float*)d_in[4];
  float* out = (float*)d_out;
  char* ws = (char*)d_ws;

  float2* sctab = (float2*)(ws);                               //  131072
  unsigned short* hsb = (unsigned short*)(ws + 131072);        // 6291456
  unsigned short* Wtq = (unsigned short*)(ws + 6422528);       // 10616832
  unsigned short* Wtk = (unsigned short*)(ws + 17039360);      // 10616832
  unsigned short* Qr  = (unsigned short*)(ws + 27656192);      // 56623104
  unsigned short* Kr  = (unsigned short*)(ws + 84279296);      // 56623104 -> 140902400

  hipLaunchKernelGGL(k_prep, dim3(11968), dim3(256), 0, stream,
                     (const float4*)hs, (ushort8*)hsb, Wq, Wk, Wtq, Wtk, sctab);
  hipLaunchKernelGGL(k2_rope, dim3(3456), dim3(256), 0, stream,
                     hsb, Wtq, Wtk, bq, bk, sctab, Qr, Kr);
  hipLaunchKernelGGL(k9_score, dim3(512), dim3(256), 0, stream, Qr, Kr, out);
}